// Round 17
// baseline (1046.124 us; speedup 1.0000x reference)
//
#include <hip/hip_runtime.h>
#include <hip/hip_bf16.h>

typedef __attribute__((ext_vector_type(8))) short bf16x8;
typedef __attribute__((ext_vector_type(4))) float f32x4;
typedef __attribute__((ext_vector_type(4))) unsigned short u16x4;
typedef __attribute__((ext_vector_type(8))) unsigned short u16x8;

#define DEVINL static __device__ __forceinline__

DEVINL unsigned short f2bf(float f) {
  union { float f; unsigned u; } a; a.f = f;
  return (unsigned short)((a.u + 0x7fffu + ((a.u >> 16) & 1u)) >> 16);  // RNE
}
DEVINL float bf2f(unsigned short s) {
  union { unsigned u; float f; } a; a.u = ((unsigned)s) << 16; return a.f;
}

typedef __attribute__((address_space(1))) const unsigned char ga_u8;
typedef __attribute__((address_space(3))) unsigned char ls_u8;

constexpr int KD = 1024;
constexpr int NKT = KD / 64;   // 16 K-tiles

// ---------------------------------------------------------------------------
// 128x128 bf16 GEMM tile with the r11 sync pattern (r15/r16): 4 waves
// (2M x 2N, 64x64 per wave, acc[4][4]), BK=64, LDS 2x32KB double-buffered ->
// 2 blocks/CU (cross-block overlap hides boundary drains - m97/m103
// mechanism; guide: 128-tile=912 TF vs 256-tile=792 TF at this structure
// class). Per K-tile: 2 K-half KSUBs; BOTH next-tile stages issued in KSUB0;
// ONE vmcnt(0)+s_barrier per tile; s_setprio around MFMA. Both-sides
// XOR-16B-chunk swizzle (rule #21). Per-wave LDS-bounce epilogue.
// K-accumulation order identical to r11/r14 -> bitwise-identical results.
// MODE 0: C bf16 +bias[col] | MODE 3: C bf16 no bias |
// MODE 4: C bf16 + rowssq[row] atomics |
// MODE 5: C bf16, v=leaky(dot + rowbias[row]), rnorm2[col] += sum v^2
// ---------------------------------------------------------------------------

#define STAGE(b_, mat_, kt_) do { \
    const unsigned short* src_ = (mat_) == 0 ? Az : Bz; \
    const int br_ = (mat_) == 0 ? m0 : n0; \
    char* dst_ = lds + (b_) * 32768 + (mat_) * 16384; \
    _Pragma("unroll") \
    for (int i_ = 0; i_ < 4; ++i_) { \
      const unsigned short* g_ = src_ + (size_t)(br_ + i_ * 32 + sr) * KD + (kt_) * 64 + gc * 8; \
      __builtin_amdgcn_global_load_lds((ga_u8*)g_, (ls_u8*)(dst_ + (i_ * 256 + wv * 64) * 16), 16, 0, 0); \
    } \
  } while (0)

#define STAGE2(b_, kt_) do { STAGE(b_, 0, kt_); STAGE(b_, 1, kt_); } while (0)

#define KSUB(b_, ks_, STG) do { \
    const char* pA_ = lds + (b_) * 32768; \
    const char* pB_ = pA_ + 16384; \
    const int co_ = (((ks_) * 4 + kg) ^ (ml & 7)) << 4; \
    bf16x8 af_[4], bf_[4]; \
    _Pragma("unroll") \
    for (int mi = 0; mi < 4; ++mi) \
      af_[mi] = *(const bf16x8*)(pA_ + (wm * 64 + mi * 16 + ml) * 128 + co_); \
    _Pragma("unroll") \
    for (int ni = 0; ni < 4; ++ni) \
      bf_[ni] = *(const bf16x8*)(pB_ + (wn * 64 + ni * 16 + ml) * 128 + co_); \
    STG; \
    __builtin_amdgcn_s_setprio(1); \
    _Pragma("unroll") \
    for (int mi = 0; mi < 4; ++mi) \
    _Pragma("unroll") \
    for (int ni = 0; ni < 4; ++ni) \
      acc[mi][ni] = __builtin_amdgcn_mfma_f32_16x16x32_bf16(af_[mi], bf_[ni], acc[mi][ni], 0, 0, 0); \
    __builtin_amdgcn_s_setprio(0); \
  } while (0)

template<int MODE>
__global__ __launch_bounds__(256, 2) void gemm8(
    const unsigned short* __restrict__ A, const unsigned short* __restrict__ B,
    const float* __restrict__ bias, void* __restrict__ Cv,
    float* __restrict__ rnorm2, int mtiles,
    long long sAz, long long sBz, long long sCz, long long sRz, long long sBiasz)
{
  alignas(16) __shared__ char lds[65536];  // [2 buf][A 16KB | B 16KB]

  const int tid = threadIdx.x;
  const int lane = tid & 63;
  const int wv = tid >> 6;        // 0..3
  const int wm = wv >> 1;         // 64-row band (0..1)
  const int wn = wv & 1;          // 64-col band (0..1)
  const int kg = lane >> 4;
  const int ml = lane & 15;

  // XCD-chunked bijective swizzle (grid always a multiple of 8);
  // nt innermost -> consecutive blocks share the A panel within one XCD L2.
  const int nwg = (int)gridDim.x;
  const int bid = (int)blockIdx.x;
  const int w = (bid & 7) * (nwg >> 3) + (bid >> 3);
  const int bpz = mtiles * 8;     // 8 N-tiles (N = 1024 / 128)
  const int z = w / bpz;
  const int rem = w - z * bpz;
  const int mt = rem >> 3, nt = rem & 7;
  const int m0 = mt * 128, n0 = nt * 128;

  const unsigned short* Az = A + (size_t)z * (size_t)sAz;
  const unsigned short* Bz = B + (size_t)z * (size_t)sBz;

  const int sr = tid >> 3;                 // 0..31
  const int gc = (tid & 7) ^ (sr & 7);

  f32x4 acc[4][4];
  const f32x4 zero4 = {0.f, 0.f, 0.f, 0.f};
#pragma unroll
  for (int i = 0; i < 4; ++i)
#pragma unroll
    for (int j = 0; j < 4; ++j) acc[i][j] = zero4;

  STAGE2(0, 0);
  asm volatile("s_waitcnt vmcnt(0)" ::: "memory");
  __builtin_amdgcn_s_barrier();

  for (int t = 0; t < NKT; ++t) {
    const int cur = t & 1;
    const int nxt = cur ^ 1;
    if (t + 1 < NKT) {
      KSUB(cur, 0, STAGE2(nxt, t + 1));   // all 8 next-tile loads issued here
      KSUB(cur, 1, );
    } else {
      KSUB(cur, 0, );
      KSUB(cur, 1, );
    }
    asm volatile("s_waitcnt vmcnt(0)" ::: "memory");
    __builtin_amdgcn_s_barrier();
  }

  // ---------------- epilogue: per-wave-private LDS bounce ----------------
  // acc frag layout: col = ni*16 + ml, row = kg*4 + j  [m89]
  float* ew = (float*)(lds + wv * 4352);     // [16][68] f32, private per wave
  const int erow = lane >> 3;                // 0..7
  const int ec8 = (lane & 7) * 8;            // col base 0..56
  const int ncol0 = n0 + wn * 64;

  if (MODE == 5) {  // v = leaky(dot + rowbias); rnorm2[col] += sum v^2
    const float* cb = bias + (size_t)z * (size_t)sBiasz;
    f32x4 cb4[4];
#pragma unroll
    for (int mi = 0; mi < 4; ++mi)
      cb4[mi] = *(const f32x4*)(cb + m0 + wm * 64 + mi * 16 + kg * 4);
    float* rn = rnorm2 + (size_t)z * (size_t)sRz;
#pragma unroll
    for (int ni = 0; ni < 4; ++ni) {
      float cs = 0.f;
#pragma unroll
      for (int mi = 0; mi < 4; ++mi)
#pragma unroll
        for (int j = 0; j < 4; ++j) {
          float v = acc[mi][ni][j] + cb4[mi][j];
          v = v >= 0.f ? v : 0.1f * v;   // LeakyReLU(0.1)
          acc[mi][ni][j] = v;
          cs += v * v;
        }
      cs += __shfl_xor(cs, 16);
      cs += __shfl_xor(cs, 32);
      if (kg == 0) atomicAdd(&rn[ncol0 + ni * 16 + ml], cs);
    }
  }

  f32x4 bv0 = zero4, bv1 = zero4;
  if (MODE == 0) {
    bv0 = *(const f32x4*)(bias + ncol0 + ec8);
    bv1 = *(const f32x4*)(bias + ncol0 + ec8 + 4);
  }

  float* rsq = (MODE == 4) ? rnorm2 + (size_t)z * (size_t)sRz : nullptr;

#pragma unroll
  for (int mi = 0; mi < 4; ++mi) {
#pragma unroll
    for (int ni = 0; ni < 4; ++ni)
#pragma unroll
      for (int j = 0; j < 4; ++j)
        ew[(kg * 4 + j) * 68 + ni * 16 + ml] = acc[mi][ni][j];
    const int rb = m0 + wm * 64 + mi * 16;
#pragma unroll
    for (int i = 0; i < 2; ++i) {
      const int r = erow + 8 * i;
      f32x4 x = *(const f32x4*)(&ew[r * 68 + ec8]);
      f32x4 y = *(const f32x4*)(&ew[r * 68 + ec8 + 4]);
      if (MODE == 4) {
        float ss = x[0]*x[0] + x[1]*x[1] + x[2]*x[2] + x[3]*x[3] +
                   y[0]*y[0] + y[1]*y[1] + y[2]*y[2] + y[3]*y[3];
        ss += __shfl_xor(ss, 1);
        ss += __shfl_xor(ss, 2);
        ss += __shfl_xor(ss, 4);
        if ((lane & 7) == 0) atomicAdd(&rsq[rb + r], ss);
      }
      unsigned short* C = (unsigned short*)Cv + (size_t)z * (size_t)sCz;
      union { unsigned short s[8]; u16x8 v; } u;
      u.s[0]=f2bf(x[0]+bv0[0]); u.s[1]=f2bf(x[1]+bv0[1]);
      u.s[2]=f2bf(x[2]+bv0[2]); u.s[3]=f2bf(x[3]+bv0[3]);
      u.s[4]=f2bf(y[0]+bv1[0]); u.s[5]=f2bf(y[1]+bv1[1]);
      u.s[6]=f2bf(y[2]+bv1[2]); u.s[7]=f2bf(y[3]+bv1[3]);
      *(u16x8*)(C + (size_t)(rb + r) * 1024 + ncol0 + ec8) = u.v;
    }
  }
}

// W (f32, [e][d]) -> WT (bf16, [d][e])
__global__ __launch_bounds__(256) void wT_k(
    const float* __restrict__ W, unsigned short* __restrict__ WT)
{
  __shared__ float tile[32][36];
  const int t = threadIdx.x;
  const int e0 = blockIdx.x * 32, d0 = blockIdx.y * 32;
  const int r = t >> 3, c4 = (t & 7) * 4;
  f32x4 v = *(const f32x4*)(W + (size_t)(e0 + r) * 1024 + d0 + c4);
  *(f32x4*)(&tile[r][c4]) = v;
  __syncthreads();
  u16x4 o;
  o[0] = f2bf(tile[c4 + 0][r]); o[1] = f2bf(tile[c4 + 1][r]);
  o[2] = f2bf(tile[c4 + 2][r]); o[3] = f2bf(tile[c4 + 3][r]);
  *(u16x4*)(WT + (size_t)(d0 + r) * 1024 + e0 + c4) = o;
}

// ctx (f32, [s][d]) -> ctxT (bf16, [d][s]) AND ctx_bf16 (bf16, [s][d])
__global__ __launch_bounds__(256) void convert_ctx_k(
    const float* __restrict__ src, unsigned short* __restrict__ dstT,
    unsigned short* __restrict__ dstR)
{
  __shared__ float tile[32][36];
  const int t = threadIdx.x;
  const int s0 = blockIdx.x * 32, d0 = blockIdx.y * 32;
  const float* S = src + (size_t)blockIdx.z * 1048576;
  unsigned short* DT = dstT + (size_t)blockIdx.z * 1048576;
  unsigned short* DR = dstR + (size_t)blockIdx.z * 1048576;
  const int s = t >> 3, d4 = (t & 7) * 4;
  f32x4 v = *(const f32x4*)(S + (size_t)(s0 + s) * 1024 + d0 + d4);
  u16x4 r;
  r[0] = f2bf(v[0]); r[1] = f2bf(v[1]); r[2] = f2bf(v[2]); r[3] = f2bf(v[3]);
  *(u16x4*)(DR + (size_t)(s0 + s) * 1024 + d0 + d4) = r;
  *(f32x4*)(&tile[s][d4]) = v;
  __syncthreads();
  const int d = t >> 3, s4 = (t & 7) * 4;
  u16x4 o;
  o[0] = f2bf(tile[s4 + 0][d]); o[1] = f2bf(tile[s4 + 1][d]);
  o[2] = f2bf(tile[s4 + 2][d]); o[3] = f2bf(tile[s4 + 3][d]);
  *(u16x4*)(DT + (size_t)(d0 + d) * 1024 + s0 + s4) = o;
}

// out[r] = Mbf[r] . vec   (one block per row; Mbf bf16 row-major [1024][1024])
__global__ __launch_bounds__(256) void rowdot_k(
    const unsigned short* __restrict__ Mbf, const float* __restrict__ vec,
    float* __restrict__ outv)
{
  __shared__ float shs[4];
  const int t = threadIdx.x;
  const unsigned short* row = Mbf + (size_t)blockIdx.x * 1024;
  u16x4 a = *(const u16x4*)(row + t * 4);
  f32x4 b = *(const f32x4*)(vec + t * 4);
  float d = bf2f(a[0]) * b[0] + bf2f(a[1]) * b[1] +
            bf2f(a[2]) * b[2] + bf2f(a[3]) * b[3];
#pragma unroll
  for (int o = 32; o; o >>= 1) d += __shfl_xor(d, o);
  if ((t & 63) == 0) shs[t >> 6] = d;
  __syncthreads();
  if (t == 0) outv[blockIdx.x] = shs[0] + shs[1] + shs[2] + shs[3];
}

// out[0] = a . b  (single block, 1024 elems)
__global__ __launch_bounds__(256) void dot1_k(
    const float* __restrict__ a, const float* __restrict__ b,
    float* __restrict__ outv)
{
  __shared__ float shs[4];
  const int t = threadIdx.x;
  f32x4 x = ((const f32x4*)a)[t];
  f32x4 y = ((const f32x4*)b)[t];
  float d = x[0]*y[0] + x[1]*y[1] + x[2]*y[2] + x[3]*y[3];
#pragma unroll
  for (int o = 32; o; o >>= 1) d += __shfl_xor(d, o);
  if ((t & 63) == 0) shs[t >> 6] = d;
  __syncthreads();
  if (t == 0) outv[0] = shs[0] + shs[1] + shs[2] + shs[3];
}

// one block (128 thr) per q-row: qbf = bf16(q);  cq[row] = q . vb + bqbk
__global__ __launch_bounds__(128) void cvtq_dot_k(
    const float* __restrict__ q, const float* __restrict__ vb,
    const float* __restrict__ bqbk, unsigned short* __restrict__ qbf,
    float* __restrict__ cq)
{
  __shared__ float sh[2];
  const int t = threadIdx.x;
  const size_t base = (size_t)blockIdx.x * 1024 + t * 8;
  f32x4 x = *(const f32x4*)(q + base);
  f32x4 y = *(const f32x4*)(q + base + 4);
  f32x4 v0 = *(const f32x4*)(vb + t * 8);
  f32x4 v1 = *(const f32x4*)(vb + t * 8 + 4);
  union { unsigned short s[8]; u16x8 v; } u;
  u.s[0]=f2bf(x[0]); u.s[1]=f2bf(x[1]); u.s[2]=f2bf(x[2]); u.s[3]=f2bf(x[3]);
  u.s[4]=f2bf(y[0]); u.s[5]=f2bf(y[1]); u.s[6]=f2bf(y[2]); u.s[7]=f2bf(y[3]);
  *(u16x8*)(qbf + base) = u.v;
  float d = x[0]*v0[0] + x[1]*v0[1] + x[2]*v0[2] + x[3]*v0[3] +
            y[0]*v1[0] + y[1]*v1[1] + y[2]*v1[2] + y[3]*v1[3];
#pragma unroll
  for (int o = 32; o; o >>= 1) d += __shfl_xor(d, o);
  if ((t & 63) == 0) sh[t >> 6] = d;
  __syncthreads();
  if (t == 0) cq[blockIdx.x] = sh[0] + sh[1] + bqbk[0];
}

// one block per (batch-in-chunk, q): softmax over s of smooth*S/(sqrt(rn)+eps)
// S is bf16 -> P bf16
__global__ __launch_bounds__(256) void softmax_k(
    const unsigned short* __restrict__ S, const float* __restrict__ rnorm2,
    const float* __restrict__ smoothp, unsigned short* __restrict__ P)
{
  __shared__ float shm[4], shs[4];
  const int t = threadIdx.x;
  const int z = blockIdx.x >> 9;            // QL = 512
  const float sm = *smoothp;
  u16x4 sr = ((const u16x4*)(S + (size_t)blockIdx.x * 1024))[t];
  f32x4 r4 = ((const f32x4*)(rnorm2 + (size_t)z * 1024))[t];
  f32x4 lg;
  lg[0] = sm * bf2f(sr[0]) / (sqrtf(r4[0]) + 1e-8f);
  lg[1] = sm * bf2f(sr[1]) / (sqrtf(r4[1]) + 1e-8f);
  lg[2] = sm * bf2f(sr[2]) / (sqrtf(r4[2]) + 1e-8f);
  lg[3] = sm * bf2f(sr[3]) / (sqrtf(r4[3]) + 1e-8f);
  float mx = fmaxf(fmaxf(lg[0], lg[1]), fmaxf(lg[2], lg[3]));
#pragma unroll
  for (int o = 32; o; o >>= 1) mx = fmaxf(mx, __shfl_xor(mx, o));
  if ((t & 63) == 0) shm[t >> 6] = mx;
  __syncthreads();
  mx = fmaxf(fmaxf(shm[0], shm[1]), fmaxf(shm[2], shm[3]));
  f32x4 e;
  e[0] = __expf(lg[0] - mx); e[1] = __expf(lg[1] - mx);
  e[2] = __expf(lg[2] - mx); e[3] = __expf(lg[3] - mx);
  float sum = e[0] + e[1] + e[2] + e[3];
#pragma unroll
  for (int o = 32; o; o >>= 1) sum += __shfl_xor(sum, o);
  if ((t & 63) == 0) shs[t >> 6] = sum;
  __syncthreads();
  sum = shs[0] + shs[1] + shs[2] + shs[3];
  float inv = 1.f / sum;
  u16x4 p;
  p[0] = f2bf(e[0] * inv); p[1] = f2bf(e[1] * inv);
  p[2] = f2bf(e[2] * inv); p[3] = f2bf(e[3] * inv);
  ((u16x4*)(P + (size_t)blockIdx.x * 1024))[t] = p;
}

// one block per row: out = wcbf / (sqrt(rowssq)+1e-8)
__global__ __launch_bounds__(256) void l2fin_k(
    const unsigned short* __restrict__ Wb, const float* __restrict__ rssq,
    float* __restrict__ O)
{
  const int t = threadIdx.x;
  const size_t base = (size_t)blockIdx.x * 1024 + t * 4;
  u16x4 w = *(const u16x4*)(Wb + base);
  float inv = 1.f / (sqrtf(rssq[blockIdx.x]) + 1e-8f);
  f32x4 o = { bf2f(w[0]) * inv, bf2f(w[1]) * inv,
              bf2f(w[2]) * inv, bf2f(w[3]) * inv };
  *(f32x4*)(O + base) = o;
}

extern "C" void kernel_launch(void* const* d_in, const int* in_sizes, int n_in,
                              void* d_out, int out_size, void* d_ws, size_t ws_size,
                              hipStream_t stream)
{
  (void)in_sizes; (void)n_in; (void)out_size;
  const float* query   = (const float*)d_in[0];  // [128][512][1024]
  const float* context = (const float*)d_in[1];  // [128][1024][1024]
  const float* Wq = (const float*)d_in[2];
  const float* bq = (const float*)d_in[3];
  const float* Wk = (const float*)d_in[4];
  const float* bk = (const float*)d_in[5];
  const float* smooth = (const float*)d_in[6];
  float* out = (float*)d_out;

  const int B = 128, QL = 512, SL = 1024, D = 1024;

  // per-batch scratch: qbf + ctxbf + ctxT + ubf/P + Sbf16(+wcbf alias) + rn + rsq + cq
  const size_t perB =
      (size_t)QL * D * 2 + (size_t)SL * D * 2 + (size_t)D * SL * 2 +
      (size_t)QL * D * 2 + (size_t)QL * SL * 2 +
      (size_t)SL * 4 + (size_t)QL * 4 + (size_t)QL * 4 + 4096;
  // fixed: wqT + wkT + WuT + cu + vb + bqbk
  const size_t fixed = 3 * (size_t)D * D * 2 + 2 * (size_t)D * 4 + 16384;
  size_t usable = ws_size > fixed ? ws_size - fixed : 0;
  int C = (int)(usable / perB);
  if (C > B) C = B;
  if (C < 1) C = 1;

  char* p = (char*)d_ws;
  auto alloc = [&](size_t bytes) {
    char* r = p; p += (bytes + 255) & ~(size_t)255; return r;
  };
  unsigned short* wqT  = (unsigned short*)alloc((size_t)D * D * 2);
  unsigned short* wkT  = (unsigned short*)alloc((size_t)D * D * 2);
  unsigned short* WuT  = (unsigned short*)alloc((size_t)D * D * 2);
  float* cu   = (float*)alloc((size_t)D * 4);
  float* vb   = (float*)alloc((size_t)D * 4);
  float* bqbk = (float*)alloc(256);
  unsigned short* qbf  = (unsigned short*)alloc((size_t)C * QL * D * 2);
  unsigned short* ctxbf= (unsigned short*)alloc((size_t)C * SL * D * 2);
  unsigned short* ctxT = (unsigned short*)alloc((size_t)C * D * SL * 2);
  unsigned short* ubf  = (unsigned short*)alloc((size_t)C * QL * D * 2);  // later P
  unsigned short* Sbuf = (unsigned short*)alloc((size_t)C * QL * SL * 2); // bf16 S, later wcbf
  float* rn   = (float*)alloc((size_t)C * SL * 4);   // rn and rsq adjacent:
  float* rsq  = (float*)alloc((size_t)C * QL * 4);   //   one merged memset
  float* cq   = (float*)alloc((size_t)C * QL * 4);
  const size_t zspan = (size_t)((char*)(rsq + (size_t)C * QL) - (char*)rn);

  // one-time weight prep
  wT_k<<<dim3(32, 32), 256, 0, stream>>>(Wq, wqT);
  wT_k<<<dim3(32, 32), 256, 0, stream>>>(Wk, wkT);
  rowdot_k<<<dim3(D), 256, 0, stream>>>(wkT, bq, cu);   // cu = bq @ Wk
  rowdot_k<<<dim3(D), 256, 0, stream>>>(wqT, bk, vb);   // vb = Wq^T bk
  dot1_k<<<dim3(1), 256, 0, stream>>>(bq, bk, bqbk);
  // WuT[d2][d1] = sum_e Wk[e][d2] Wq[e][d1]   (M=1024 -> 8 m-tiles, grid 64)
  gemm8<3><<<dim3(64), 256, 0, stream>>>(
      wkT, wqT, nullptr, WuT, nullptr, 8, 0, 0, 0, 0, 0);

  for (int b0 = 0; b0 < B; b0 += C) {
    const int Cc = (B - b0) < C ? (B - b0) : C;
    hipMemsetAsync(rn, 0, zspan, stream);
    // fused: qbf = bf16(query); cq = q.vb + bq.bk
    cvtq_dot_k<<<dim3(Cc * QL), 128, 0, stream>>>(
        query + (size_t)b0 * QL * D, vb, bqbk, qbf, cq);
    convert_ctx_k<<<dim3(32, 32, Cc), 256, 0, stream>>>(
        context + (size_t)b0 * SL * D, ctxT, ctxbf);
    // u = q @ Wu + cu  (bf16)   [M=512 -> 4 m-tiles, grid Cc*32]
    gemm8<0><<<dim3(Cc * 32), 256, 0, stream>>>(
        qbf, WuT, cu, ubf, nullptr, 4,
        (long long)QL * D, 0, (long long)QL * D, 0, 0);
    // S[q][s] (bf16) = leaky(u . ctx + c[q]);  rnorm2[s] += sum_q leaky^2
    gemm8<5><<<dim3(Cc * 32), 256, 0, stream>>>(
        ubf, ctxbf, cq, Sbuf, rn, 4,
        (long long)QL * D, (long long)SL * D, (long long)QL * SL,
        (long long)SL, (long long)QL);
    softmax_k<<<Cc * QL, 256, 0, stream>>>(Sbuf, rn, smooth, ubf /* P */);
    // wc(bf16) = P @ ctxT^T ; rsq[q] += row sum of squares (f32-accurate)
    gemm8<4><<<dim3(Cc * 32), 256, 0, stream>>>(
        ubf /* P */, ctxT, nullptr, Sbuf /* wcbf */, rsq, 4,
        (long long)QL * SL, (long long)D * SL, (long long)QL * D,
        (long long)QL, 0);
    // out = wcbf / (sqrt(rsq)+eps)
    l2fin_k<<<dim3(Cc * QL), 256, 0, stream>>>(
        Sbuf, rsq, out + (size_t)b0 * QL * D);
  }
}

// Round 18
// 957.510 us; speedup vs baseline: 1.0925x; 1.0925x over previous
//
#include <hip/hip_runtime.h>
#include <hip/hip_bf16.h>

typedef __attribute__((ext_vector_type(8))) short bf16x8;
typedef __attribute__((ext_vector_type(4))) float f32x4;
typedef __attribute__((ext_vector_type(4))) unsigned short u16x4;
typedef __attribute__((ext_vector_type(8))) unsigned short u16x8;

#define DEVINL static __device__ __forceinline__

DEVINL unsigned short f2bf(float f) {
  union { float f; unsigned u; } a; a.f = f;
  return (unsigned short)((a.u + 0x7fffu + ((a.u >> 16) & 1u)) >> 16);  // RNE
}
DEVINL float bf2f(unsigned short s) {
  union { unsigned u; float f; } a; a.u = ((unsigned)s) << 16; return a.f;
}

typedef __attribute__((address_space(1))) const unsigned char ga_u8;
typedef __attribute__((address_space(3))) unsigned char ls_u8;

constexpr int KD = 1024;
constexpr int NKT = KD / 64;   // 16 K-tiles

// ---------------------------------------------------------------------------
// 256x256 bf16 GEMM (r11/r14 configuration — measured optimum 959us):
// 8 waves (2M x 4N), BK=64, LDS 2x64KB double-buffered; per K-tile 2 K-half
// phases; BOTH next-tile stages issued in KSUB0 (full-tile prefetch slack ->
// boundary vmcnt(0) nearly free); ONE vmcnt(0)+s_barrier per K-tile;
// s_setprio(1) around MFMA clusters.
// Both-sides XOR-16B-chunk swizzle (rule #21). Per-wave LDS-bounce epilogue.
// Variant sweep (all regressed vs this): BK=32 quad-buf (r6, -5%), 256x128
// occupancy-first (r8, -9%), asymmetric rings (r12, -3%), no-setprio
// (r13, -2%), 128x128 tile (r17, -9%).
// MODE 0: C bf16 +bias[col] | MODE 3: C bf16 no bias |
// MODE 4: C bf16 + rowssq[row] atomics |
// MODE 5: C bf16, v=leaky(dot + rowbias[row]), rnorm2[col] += sum v^2
// ---------------------------------------------------------------------------

#define STAGE(b_, mat_, kt_) do { \
    const unsigned short* src_ = (mat_) == 0 ? Az : Bz; \
    const int br_ = (mat_) == 0 ? m0 : n0; \
    char* dst_ = lds + (b_) * 65536 + (mat_) * 32768; \
    _Pragma("unroll") \
    for (int i_ = 0; i_ < 4; ++i_) { \
      const unsigned short* g_ = src_ + (size_t)(br_ + i_ * 64 + sr) * KD + (kt_) * 64 + gc * 8; \
      __builtin_amdgcn_global_load_lds((ga_u8*)g_, (ls_u8*)(dst_ + (i_ * 512 + wv * 64) * 16), 16, 0, 0); \
    } \
  } while (0)

#define STAGE2(b_, kt_) do { STAGE(b_, 0, kt_); STAGE(b_, 1, kt_); } while (0)

#define KSUB(b_, ks_, STG) do { \
    const char* pA_ = lds + (b_) * 65536; \
    const char* pB_ = pA_ + 32768; \
    const int co_ = (((ks_) * 4 + kg) ^ (ml & 7)) << 4; \
    bf16x8 af_[8], bf_[4]; \
    _Pragma("unroll") \
    for (int mi = 0; mi < 8; ++mi) \
      af_[mi] = *(const bf16x8*)(pA_ + (wm * 128 + mi * 16 + ml) * 128 + co_); \
    _Pragma("unroll") \
    for (int ni = 0; ni < 4; ++ni) \
      bf_[ni] = *(const bf16x8*)(pB_ + (wn * 64 + ni * 16 + ml) * 128 + co_); \
    STG; \
    __builtin_amdgcn_s_setprio(1); \
    _Pragma("unroll") \
    for (int mi = 0; mi < 8; ++mi) \
    _Pragma("unroll") \
    for (int ni = 0; ni < 4; ++ni) \
      acc[mi][ni] = __builtin_amdgcn_mfma_f32_16x16x32_bf16(af_[mi], bf_[ni], acc[mi][ni], 0, 0, 0); \
    __builtin_amdgcn_s_setprio(0); \
  } while (0)

template<int MODE>
__global__ __launch_bounds__(512, 2) void gemm8(
    const unsigned short* __restrict__ A, const unsigned short* __restrict__ B,
    const float* __restrict__ bias, void* __restrict__ Cv,
    float* __restrict__ rnorm2, int mtiles,
    long long sAz, long long sBz, long long sCz, long long sRz, long long sBiasz)
{
  alignas(16) __shared__ char lds[131072];  // [2 buf][A|B][256 rows * 128 B]

  const int tid = threadIdx.x;
  const int lane = tid & 63;
  const int wv = tid >> 6;        // 0..7
  const int wm = wv >> 2;         // A-half (128 rows)
  const int wn = wv & 3;          // 64-col slice
  const int kg = lane >> 4;
  const int ml = lane & 15;

  // XCD-chunked bijective swizzle (grid always a multiple of 8)
  const int nwg = (int)gridDim.x;
  const int bid = (int)blockIdx.x;
  const int w = (bid & 7) * (nwg >> 3) + (bid >> 3);
  const int bpz = mtiles * 4;
  const int z = w / bpz;
  const int rem = w - z * bpz;
  const int mt = rem >> 2, nt = rem & 3;
  const int m0 = mt * 256, n0 = nt * 256;

  const unsigned short* Az = A + (size_t)z * (size_t)sAz;
  const unsigned short* Bz = B + (size_t)z * (size_t)sBz;

  const int sr = tid >> 3;
  const int gc = (tid & 7) ^ (sr & 7);

  f32x4 acc[8][4];
  const f32x4 zero4 = {0.f, 0.f, 0.f, 0.f};
#pragma unroll
  for (int i = 0; i < 8; ++i)
#pragma unroll
    for (int j = 0; j < 4; ++j) acc[i][j] = zero4;

  STAGE2(0, 0);
  asm volatile("s_waitcnt vmcnt(0)" ::: "memory");
  __builtin_amdgcn_s_barrier();

  for (int t = 0; t < NKT; ++t) {
    const int cur = t & 1;
    const int nxt = cur ^ 1;
    if (t + 1 < NKT) {
      KSUB(cur, 0, STAGE2(nxt, t + 1));   // all 8 next-tile loads issued here
      KSUB(cur, 1, );
    } else {
      KSUB(cur, 0, );
      KSUB(cur, 1, );
    }
    asm volatile("s_waitcnt vmcnt(0)" ::: "memory");
    __builtin_amdgcn_s_barrier();
  }

  // ---------------- epilogue: per-wave-private LDS bounce ----------------
  // acc frag layout: col = ni*16 + ml, row = kg*4 + j  [m89]
  float* ew = (float*)(lds + wv * 4352);     // [16][68] f32, private per wave
  const int erow = lane >> 3;                // 0..7
  const int ec8 = (lane & 7) * 8;            // col base 0..56
  const int ncol0 = n0 + wn * 64;

  if (MODE == 5) {  // v = leaky(dot + rowbias); rnorm2[col] += sum v^2
    const float* cb = bias + (size_t)z * (size_t)sBiasz;
    f32x4 cb4[8];
#pragma unroll
    for (int mi = 0; mi < 8; ++mi)
      cb4[mi] = *(const f32x4*)(cb + m0 + wm * 128 + mi * 16 + kg * 4);
    float* rn = rnorm2 + (size_t)z * (size_t)sRz;
#pragma unroll
    for (int ni = 0; ni < 4; ++ni) {
      float cs = 0.f;
#pragma unroll
      for (int mi = 0; mi < 8; ++mi)
#pragma unroll
        for (int j = 0; j < 4; ++j) {
          float v = acc[mi][ni][j] + cb4[mi][j];
          v = v >= 0.f ? v : 0.1f * v;   // LeakyReLU(0.1)
          acc[mi][ni][j] = v;
          cs += v * v;
        }
      cs += __shfl_xor(cs, 16);
      cs += __shfl_xor(cs, 32);
      if (kg == 0) atomicAdd(&rn[ncol0 + ni * 16 + ml], cs);
    }
  }

  f32x4 bv0 = zero4, bv1 = zero4;
  if (MODE == 0) {
    bv0 = *(const f32x4*)(bias + ncol0 + ec8);
    bv1 = *(const f32x4*)(bias + ncol0 + ec8 + 4);
  }

  float* rsq = (MODE == 4) ? rnorm2 + (size_t)z * (size_t)sRz : nullptr;

#pragma unroll
  for (int mi = 0; mi < 8; ++mi) {
#pragma unroll
    for (int ni = 0; ni < 4; ++ni)
#pragma unroll
      for (int j = 0; j < 4; ++j)
        ew[(kg * 4 + j) * 68 + ni * 16 + ml] = acc[mi][ni][j];
    const int rb = m0 + wm * 128 + mi * 16;
#pragma unroll
    for (int i = 0; i < 2; ++i) {
      const int r = erow + 8 * i;
      f32x4 x = *(const f32x4*)(&ew[r * 68 + ec8]);
      f32x4 y = *(const f32x4*)(&ew[r * 68 + ec8 + 4]);
      if (MODE == 4) {
        float ss = x[0]*x[0] + x[1]*x[1] + x[2]*x[2] + x[3]*x[3] +
                   y[0]*y[0] + y[1]*y[1] + y[2]*y[2] + y[3]*y[3];
        ss += __shfl_xor(ss, 1);
        ss += __shfl_xor(ss, 2);
        ss += __shfl_xor(ss, 4);
        if ((lane & 7) == 0) atomicAdd(&rsq[rb + r], ss);
      }
      unsigned short* C = (unsigned short*)Cv + (size_t)z * (size_t)sCz;
      union { unsigned short s[8]; u16x8 v; } u;
      u.s[0]=f2bf(x[0]+bv0[0]); u.s[1]=f2bf(x[1]+bv0[1]);
      u.s[2]=f2bf(x[2]+bv0[2]); u.s[3]=f2bf(x[3]+bv0[3]);
      u.s[4]=f2bf(y[0]+bv1[0]); u.s[5]=f2bf(y[1]+bv1[1]);
      u.s[6]=f2bf(y[2]+bv1[2]); u.s[7]=f2bf(y[3]+bv1[3]);
      *(u16x8*)(C + (size_t)(rb + r) * 1024 + ncol0 + ec8) = u.v;
    }
  }
}

// W (f32, [e][d]) -> WT (bf16, [d][e])
__global__ __launch_bounds__(256) void wT_k(
    const float* __restrict__ W, unsigned short* __restrict__ WT)
{
  __shared__ float tile[32][36];
  const int t = threadIdx.x;
  const int e0 = blockIdx.x * 32, d0 = blockIdx.y * 32;
  const int r = t >> 3, c4 = (t & 7) * 4;
  f32x4 v = *(const f32x4*)(W + (size_t)(e0 + r) * 1024 + d0 + c4);
  *(f32x4*)(&tile[r][c4]) = v;
  __syncthreads();
  u16x4 o;
  o[0] = f2bf(tile[c4 + 0][r]); o[1] = f2bf(tile[c4 + 1][r]);
  o[2] = f2bf(tile[c4 + 2][r]); o[3] = f2bf(tile[c4 + 3][r]);
  *(u16x4*)(WT + (size_t)(d0 + r) * 1024 + e0 + c4) = o;
}

// ctx (f32, [s][d]) -> ctxT (bf16, [d][s]) AND ctx_bf16 (bf16, [s][d])
__global__ __launch_bounds__(256) void convert_ctx_k(
    const float* __restrict__ src, unsigned short* __restrict__ dstT,
    unsigned short* __restrict__ dstR)
{
  __shared__ float tile[32][36];
  const int t = threadIdx.x;
  const int s0 = blockIdx.x * 32, d0 = blockIdx.y * 32;
  const float* S = src + (size_t)blockIdx.z * 1048576;
  unsigned short* DT = dstT + (size_t)blockIdx.z * 1048576;
  unsigned short* DR = dstR + (size_t)blockIdx.z * 1048576;
  const int s = t >> 3, d4 = (t & 7) * 4;
  f32x4 v = *(const f32x4*)(S + (size_t)(s0 + s) * 1024 + d0 + d4);
  u16x4 r;
  r[0] = f2bf(v[0]); r[1] = f2bf(v[1]); r[2] = f2bf(v[2]); r[3] = f2bf(v[3]);
  *(u16x4*)(DR + (size_t)(s0 + s) * 1024 + d0 + d4) = r;
  *(f32x4*)(&tile[s][d4]) = v;
  __syncthreads();
  const int d = t >> 3, s4 = (t & 7) * 4;
  u16x4 o;
  o[0] = f2bf(tile[s4 + 0][d]); o[1] = f2bf(tile[s4 + 1][d]);
  o[2] = f2bf(tile[s4 + 2][d]); o[3] = f2bf(tile[s4 + 3][d]);
  *(u16x4*)(DT + (size_t)(d0 + d) * 1024 + s0 + s4) = o;
}

// out[r] = Mbf[r] . vec   (one block per row; Mbf bf16 row-major [1024][1024])
__global__ __launch_bounds__(256) void rowdot_k(
    const unsigned short* __restrict__ Mbf, const float* __restrict__ vec,
    float* __restrict__ outv)
{
  __shared__ float shs[4];
  const int t = threadIdx.x;
  const unsigned short* row = Mbf + (size_t)blockIdx.x * 1024;
  u16x4 a = *(const u16x4*)(row + t * 4);
  f32x4 b = *(const f32x4*)(vec + t * 4);
  float d = bf2f(a[0]) * b[0] + bf2f(a[1]) * b[1] +
            bf2f(a[2]) * b[2] + bf2f(a[3]) * b[3];
#pragma unroll
  for (int o = 32; o; o >>= 1) d += __shfl_xor(d, o);
  if ((t & 63) == 0) shs[t >> 6] = d;
  __syncthreads();
  if (t == 0) outv[blockIdx.x] = shs[0] + shs[1] + shs[2] + shs[3];
}

// out[0] = a . b  (single block, 1024 elems)
__global__ __launch_bounds__(256) void dot1_k(
    const float* __restrict__ a, const float* __restrict__ b,
    float* __restrict__ outv)
{
  __shared__ float shs[4];
  const int t = threadIdx.x;
  f32x4 x = ((const f32x4*)a)[t];
  f32x4 y = ((const f32x4*)b)[t];
  float d = x[0]*y[0] + x[1]*y[1] + x[2]*y[2] + x[3]*y[3];
#pragma unroll
  for (int o = 32; o; o >>= 1) d += __shfl_xor(d, o);
  if ((t & 63) == 0) shs[t >> 6] = d;
  __syncthreads();
  if (t == 0) outv[0] = shs[0] + shs[1] + shs[2] + shs[3];
}

// one block (128 thr) per q-row: qbf = bf16(q);  cq[row] = q . vb + bqbk
__global__ __launch_bounds__(128) void cvtq_dot_k(
    const float* __restrict__ q, const float* __restrict__ vb,
    const float* __restrict__ bqbk, unsigned short* __restrict__ qbf,
    float* __restrict__ cq)
{
  __shared__ float sh[2];
  const int t = threadIdx.x;
  const size_t base = (size_t)blockIdx.x * 1024 + t * 8;
  f32x4 x = *(const f32x4*)(q + base);
  f32x4 y = *(const f32x4*)(q + base + 4);
  f32x4 v0 = *(const f32x4*)(vb + t * 8);
  f32x4 v1 = *(const f32x4*)(vb + t * 8 + 4);
  union { unsigned short s[8]; u16x8 v; } u;
  u.s[0]=f2bf(x[0]); u.s[1]=f2bf(x[1]); u.s[2]=f2bf(x[2]); u.s[3]=f2bf(x[3]);
  u.s[4]=f2bf(y[0]); u.s[5]=f2bf(y[1]); u.s[6]=f2bf(y[2]); u.s[7]=f2bf(y[3]);
  *(u16x8*)(qbf + base) = u.v;
  float d = x[0]*v0[0] + x[1]*v0[1] + x[2]*v0[2] + x[3]*v0[3] +
            y[0]*v1[0] + y[1]*v1[1] + y[2]*v1[2] + y[3]*v1[3];
#pragma unroll
  for (int o = 32; o; o >>= 1) d += __shfl_xor(d, o);
  if ((t & 63) == 0) sh[t >> 6] = d;
  __syncthreads();
  if (t == 0) cq[blockIdx.x] = sh[0] + sh[1] + bqbk[0];
}

// one block per (batch-in-chunk, q): softmax over s of smooth*S/(sqrt(rn)+eps)
// S is bf16 -> P bf16
__global__ __launch_bounds__(256) void softmax_k(
    const unsigned short* __restrict__ S, const float* __restrict__ rnorm2,
    const float* __restrict__ smoothp, unsigned short* __restrict__ P)
{
  __shared__ float shm[4], shs[4];
  const int t = threadIdx.x;
  const int z = blockIdx.x >> 9;            // QL = 512
  const float sm = *smoothp;
  u16x4 sr = ((const u16x4*)(S + (size_t)blockIdx.x * 1024))[t];
  f32x4 r4 = ((const f32x4*)(rnorm2 + (size_t)z * 1024))[t];
  f32x4 lg;
  lg[0] = sm * bf2f(sr[0]) / (sqrtf(r4[0]) + 1e-8f);
  lg[1] = sm * bf2f(sr[1]) / (sqrtf(r4[1]) + 1e-8f);
  lg[2] = sm * bf2f(sr[2]) / (sqrtf(r4[2]) + 1e-8f);
  lg[3] = sm * bf2f(sr[3]) / (sqrtf(r4[3]) + 1e-8f);
  float mx = fmaxf(fmaxf(lg[0], lg[1]), fmaxf(lg[2], lg[3]));
#pragma unroll
  for (int o = 32; o; o >>= 1) mx = fmaxf(mx, __shfl_xor(mx, o));
  if ((t & 63) == 0) shm[t >> 6] = mx;
  __syncthreads();
  mx = fmaxf(fmaxf(shm[0], shm[1]), fmaxf(shm[2], shm[3]));
  f32x4 e;
  e[0] = __expf(lg[0] - mx); e[1] = __expf(lg[1] - mx);
  e[2] = __expf(lg[2] - mx); e[3] = __expf(lg[3] - mx);
  float sum = e[0] + e[1] + e[2] + e[3];
#pragma unroll
  for (int o = 32; o; o >>= 1) sum += __shfl_xor(sum, o);
  if ((t & 63) == 0) shs[t >> 6] = sum;
  __syncthreads();
  sum = shs[0] + shs[1] + shs[2] + shs[3];
  float inv = 1.f / sum;
  u16x4 p;
  p[0] = f2bf(e[0] * inv); p[1] = f2bf(e[1] * inv);
  p[2] = f2bf(e[2] * inv); p[3] = f2bf(e[3] * inv);
  ((u16x4*)(P + (size_t)blockIdx.x * 1024))[t] = p;
}

// one block per row: out = wcbf / (sqrt(rowssq)+1e-8)
__global__ __launch_bounds__(256) void l2fin_k(
    const unsigned short* __restrict__ Wb, const float* __restrict__ rssq,
    float* __restrict__ O)
{
  const int t = threadIdx.x;
  const size_t base = (size_t)blockIdx.x * 1024 + t * 4;
  u16x4 w = *(const u16x4*)(Wb + base);
  float inv = 1.f / (sqrtf(rssq[blockIdx.x]) + 1e-8f);
  f32x4 o = { bf2f(w[0]) * inv, bf2f(w[1]) * inv,
              bf2f(w[2]) * inv, bf2f(w[3]) * inv };
  *(f32x4*)(O + base) = o;
}

extern "C" void kernel_launch(void* const* d_in, const int* in_sizes, int n_in,
                              void* d_out, int out_size, void* d_ws, size_t ws_size,
                              hipStream_t stream)
{
  (void)in_sizes; (void)n_in; (void)out_size;
  const float* query   = (const float*)d_in[0];  // [128][512][1024]
  const float* context = (const float*)d_in[1];  // [128][1024][1024]
  const float* Wq = (const float*)d_in[2];
  const float* bq = (const float*)d_in[3];
  const float* Wk = (const float*)d_in[4];
  const float* bk = (const float*)d_in[5];
  const float* smooth = (const float*)d_in[6];
  float* out = (float*)d_out;

  const int B = 128, QL = 512, SL = 1024, D = 1024;

  // per-batch scratch: qbf + ctxbf + ctxT + ubf/P + Sbf16(+wcbf alias) + rn + rsq + cq
  const size_t perB =
      (size_t)QL * D * 2 + (size_t)SL * D * 2 + (size_t)D * SL * 2 +
      (size_t)QL * D * 2 + (size_t)QL * SL * 2 +
      (size_t)SL * 4 + (size_t)QL * 4 + (size_t)QL * 4 + 4096;
  // fixed: wqT + wkT + WuT + cu + vb + bqbk
  const size_t fixed = 3 * (size_t)D * D * 2 + 2 * (size_t)D * 4 + 16384;
  size_t usable = ws_size > fixed ? ws_size - fixed : 0;
  int C = (int)(usable / perB);
  if (C > B) C = B;
  if (C < 1) C = 1;

  char* p = (char*)d_ws;
  auto alloc = [&](size_t bytes) {
    char* r = p; p += (bytes + 255) & ~(size_t)255; return r;
  };
  unsigned short* wqT  = (unsigned short*)alloc((size_t)D * D * 2);
  unsigned short* wkT  = (unsigned short*)alloc((size_t)D * D * 2);
  unsigned short* WuT  = (unsigned short*)alloc((size_t)D * D * 2);
  float* cu   = (float*)alloc((size_t)D * 4);
  float* vb   = (float*)alloc((size_t)D * 4);
  float* bqbk = (float*)alloc(256);
  unsigned short* qbf  = (unsigned short*)alloc((size_t)C * QL * D * 2);
  unsigned short* ctxbf= (unsigned short*)alloc((size_t)C * SL * D * 2);
  unsigned short* ctxT = (unsigned short*)alloc((size_t)C * D * SL * 2);
  unsigned short* ubf  = (unsigned short*)alloc((size_t)C * QL * D * 2);  // later P
  unsigned short* Sbuf = (unsigned short*)alloc((size_t)C * QL * SL * 2); // bf16 S, later wcbf
  float* rn   = (float*)alloc((size_t)C * SL * 4);   // rn and rsq adjacent:
  float* rsq  = (float*)alloc((size_t)C * QL * 4);   //   one merged memset
  float* cq   = (float*)alloc((size_t)C * QL * 4);
  const size_t zspan = (size_t)((char*)(rsq + (size_t)C * QL) - (char*)rn);

  // one-time weight prep
  wT_k<<<dim3(32, 32), 256, 0, stream>>>(Wq, wqT);
  wT_k<<<dim3(32, 32), 256, 0, stream>>>(Wk, wkT);
  rowdot_k<<<dim3(D), 256, 0, stream>>>(wkT, bq, cu);   // cu = bq @ Wk
  rowdot_k<<<dim3(D), 256, 0, stream>>>(wqT, bk, vb);   // vb = Wq^T bk
  dot1_k<<<dim3(1), 256, 0, stream>>>(bq, bk, bqbk);
  // WuT[d2][d1] = sum_e Wk[e][d2] Wq[e][d1]
  gemm8<3><<<dim3(16), 512, 0, stream>>>(
      wkT, wqT, nullptr, WuT, nullptr, 4, 0, 0, 0, 0, 0);

  for (int b0 = 0; b0 < B; b0 += C) {
    const int Cc = (B - b0) < C ? (B - b0) : C;
    hipMemsetAsync(rn, 0, zspan, stream);
    // fused: qbf = bf16(query); cq = q.vb + bq.bk
    cvtq_dot_k<<<dim3(Cc * QL), 128, 0, stream>>>(
        query + (size_t)b0 * QL * D, vb, bqbk, qbf, cq);
    convert_ctx_k<<<dim3(32, 32, Cc), 256, 0, stream>>>(
        context + (size_t)b0 * SL * D, ctxT, ctxbf);
    // u = q @ Wu + cu  (bf16)
    gemm8<0><<<dim3(Cc * 8), 512, 0, stream>>>(
        qbf, WuT, cu, ubf, nullptr, 2,
        (long long)QL * D, 0, (long long)QL * D, 0, 0);
    // S[q][s] (bf16) = leaky(u . ctx + c[q]);  rnorm2[s] += sum_q leaky^2
    gemm8<5><<<dim3(Cc * 8), 512, 0, stream>>>(
        ubf, ctxbf, cq, Sbuf, rn, 2,
        (long long)QL * D, (long long)SL * D, (long long)QL * SL,
        (long long)SL, (long long)QL);
    softmax_k<<<Cc * QL, 256, 0, stream>>>(Sbuf, rn, smooth, ubf /* P */);
    // wc(bf16) = P @ ctxT^T ; rsq[q] += row sum of squares (f32-accurate)
    gemm8<4><<<dim3(Cc * 8), 512, 0, stream>>>(
        ubf /* P */, ctxT, nullptr, Sbuf /* wcbf */, rsq, 2,
        (long long)QL * SL, (long long)D * SL, (long long)QL * D,
        (long long)QL, 0);
    // out = wcbf / (sqrt(rsq)+eps)
    l2fin_k<<<dim3(Cc * QL), 256, 0, stream>>>(
        Sbuf, rsq, out + (size_t)b0 * QL * D);
  }
}